// Round 2
// baseline (206.149 us; speedup 1.0000x reference)
//
#include <hip/hip_runtime.h>

// PPolyIntSoftmax, rows of 512. Exact float64-numpy replication.
// R11: 2 rows per wave (ILP/MLP doubling) on top of R10's persistent blocks.
//  Diagnosis from R10: latency-bound, not VALU-bound (VALU issue dropped 28%,
//  duration flat). Per wave-iteration the serial chain (load -> floor -> DPP
//  max -> readlane -> LDS gather -> DPP sum -> readlane -> f64 div -> store)
//  stalls ~95% of the time with only 2KB of reads in flight per wave.
//  Fix: each wave owns TWO rows per iteration -> two independent chains
//  interleave (2x MLP + 2x ILP through every wave-wide serialization point),
//  halving iterations per wave.
//  - 32-bit indexing in the hot loop; offsets fold to offset:1024/2048/3072.
//  - LUT built once per block; single __syncthreads; steady loop barrier-free.
//  - exact-integer semantics unchanged from R9/R10 (absmax=0): fdiv_floor
//    two-fma correction, LUT Horner (i32/i64 exact), DPP i32 sum,
//    factor via __ddiv_rn, (e*factor)>>25 == umulhi(e, factor<<7).

#define ROWLEN 512

typedef float nfloat4 __attribute__((ext_vector_type(4)));

#define DPP_SUM_I32(t)                                                        \
    t += __builtin_amdgcn_update_dpp(0, t, 0x111, 0xf, 0xf, true);            \
    t += __builtin_amdgcn_update_dpp(0, t, 0x112, 0xf, 0xf, true);            \
    t += __builtin_amdgcn_update_dpp(0, t, 0x114, 0xf, 0xf, true);            \
    t += __builtin_amdgcn_update_dpp(0, t, 0x118, 0xf, 0xf, true);            \
    t += __builtin_amdgcn_update_dpp(0, t, 0x142, 0xa, 0xf, true);            \
    t += __builtin_amdgcn_update_dpp(0, t, 0x143, 0xc, 0xf, true);

#define DPP_MAX_I32_STEP(m, ctrl, rmask)                                      \
    {                                                                         \
        int _sh = __builtin_amdgcn_update_dpp(m, m, ctrl, rmask, 0xf, false); \
        m = (_sh > m) ? _sh : m;                                              \
    }

#define DPP_MAX_CHAIN(m)                                                      \
    DPP_MAX_I32_STEP(m, 0x111, 0xf)                                           \
    DPP_MAX_I32_STEP(m, 0x112, 0xf)                                           \
    DPP_MAX_I32_STEP(m, 0x114, 0xf)                                           \
    DPP_MAX_I32_STEP(m, 0x118, 0xf)                                           \
    DPP_MAX_I32_STEP(m, 0x142, 0xa)                                           \
    DPP_MAX_I32_STEP(m, 0x143, 0xc)

__global__ __launch_bounds__(256, 8) void ppis_kernel(
    const float* __restrict__ x,
    const float* __restrict__ sfp,
    const float* __restrict__ lo,   // unused: structure derived analytically
    const float* __restrict__ cf,
    float* __restrict__ out,
    int nrows)
{
    __shared__ int s_e[1024];   // exp_int LUT: entry j <-> xi = j - 896

    const int tid  = threadIdx.x;
    const int lane = tid & 63;
    const int wid  = tid >> 6;

    const int nsg     = nrows >> 3;       // supergroups of 8 rows (2 rows/wave)
    const int gstride = (int)gridDim.x;

    int sg = (int)blockIdx.x;

    // ---- issue first x loads (2 rows/wave); LUT build overlaps latency ----
    const float4* xb = reinterpret_cast<const float4*>(x);
    int base = (sg * 8 + wid * 2) * (ROWLEN / 4);   // row r0 base, float4 units
    float4 va0 = xb[base + lane];
    float4 vb0 = xb[base + 64 + lane];
    float4 va1 = xb[base + 128 + lane];
    float4 vb1 = xb[base + 192 + lane];

    const float s  = sfp[0];
    const float ry = 1.0f / s;   // approx reciprocal; exactness via fma sign tests

    // ---- build LUT ONCE per block: bit-identical integer pipeline ----
    {
        int4 ev;
        int* evp = reinterpret_cast<int*>(&ev);
        const int j0 = tid * 4;
        #pragma unroll
        for (int jj = 0; jj < 4; ++jj) {
            const int j  = j0 + jj;
            const int u  = j - 768;              // u = xi + 128
            const int uc = u < 0 ? 0 : u;
            int idx = ((uc + 1) * 257) >> 12;    // == clip(searchsorted-1,0,15)
            idx = idx > 15 ? 15 : idx;
            const int c0 = (int)cf[idx * 3 + 0];
            const int c1 = (int)cf[idx * 3 + 1];
            const int c2 = (int)cf[idx * 3 + 2];
            const int xi = j - 896;              // UNCLAMPED xi
            const int r1 = c2 * xi + c1;               // |c2*xi| < 2^27: exact i32
            long long r2 = (long long)r1 * xi + c0;    // exact i64
            if (r2 < 0) r2 = 0;
            evp[jj] = (int)(r2 >> 15);
        }
        reinterpret_cast<int4*>(s_e)[tid] = ev;  // ds_write_b128
    }
    __syncthreads();            // the ONLY barrier; LUT read-only afterwards

    nfloat4* ob = reinterpret_cast<nfloat4*>(out);

    // exact floor(x/s), f32 only (validated absmax=0 since R6)
    auto fdiv_floor = [&](float xk) -> int {
        float nf = floorf(xk * ry);                 // candidate, off by <=1
        const float d = fmaf(-s, nf, xk);           // sign(x - nf*s) exact
        nf = (d < 0.0f) ? nf - 1.0f : nf;
        const float u = fmaf(-s, nf + 1.0f, xk);    // sign(x - (nf+1)s) exact
        nf = (u >= 0.0f) ? nf + 1.0f : nf;
        return (int)nf;
    };

    while (true) {
        // ---- prefetch next supergroup's 2 rows before processing current ----
        const int nxt   = sg + gstride;
        const bool more = nxt < nsg;
        const int nbase = (nxt * 8 + wid * 2) * (ROWLEN / 4);
        float4 pa0, pb0, pa1, pb1;
        if (more) {
            pa0 = xb[nbase + lane];
            pb0 = xb[nbase + 64 + lane];
            pa1 = xb[nbase + 128 + lane];
            pb1 = xb[nbase + 192 + lane];
        }

        const float xv0[8] = {va0.x, va0.y, va0.z, va0.w, vb0.x, vb0.y, vb0.z, vb0.w};
        const float xv1[8] = {va1.x, va1.y, va1.z, va1.w, vb1.x, vb1.y, vb1.z, vb1.w};

        int n0[8], n1[8];
        #pragma unroll
        for (int k = 0; k < 8; ++k) n0[k] = fdiv_floor(xv0[k]);
        #pragma unroll
        for (int k = 0; k < 8; ++k) n1[k] = fdiv_floor(xv1[k]);

        // row maxes in INT domain — two independent DPP chains interleave
        int m0 = n0[0], m1 = n1[0];
        #pragma unroll
        for (int k = 1; k < 8; ++k) {
            m0 = (n0[k] > m0) ? n0[k] : m0;
            m1 = (n1[k] > m1) ? n1[k] : m1;
        }
        DPP_MAX_CHAIN(m0)
        DPP_MAX_CHAIN(m1)
        const int mx0 = __builtin_amdgcn_readlane(m0, 63);
        const int mx1 = __builtin_amdgcn_readlane(m1, 63);

        const int joff0 = 1023 - mx0;           // j = n + joff, j <= 1023
        const int joff1 = 1023 - mx1;

        int jmin;
        {
            #pragma unroll
            for (int k = 0; k < 8; ++k) { n0[k] += joff0; n1[k] += joff1; }
            jmin = n0[0];
            #pragma unroll
            for (int k = 1; k < 8; ++k) jmin = (n0[k] < jmin) ? n0[k] : jmin;
            #pragma unroll
            for (int k = 0; k < 8; ++k) jmin = (n1[k] < jmin) ? n1[k] : jmin;
        }

        int e0[8], e1[8];
        int t0 = 0, t1 = 0;
        if (!__any(jmin < 0)) {
            // fast path: both rows fully inside the LUT domain
            #pragma unroll
            for (int k = 0; k < 8; ++k) {
                e0[k] = s_e[n0[k]];
                e1[k] = s_e[n1[k]];
                t0 += e0[k];
                t1 += e1[k];
            }
        } else {
            // rare: row span > 1023 ints -> exact i64 Horner at actual xi
            // (identical formulas to the LUT build -> bit-identical values)
            #pragma unroll 1
            for (int k = 0; k < 8; ++k) {
                {
                    const int u  = n0[k] - 768;
                    const int uc = u < 0 ? 0 : u;
                    int idx = ((uc + 1) * 257) >> 12;
                    idx = idx > 15 ? 15 : idx;
                    const long long c0 = (long long)(int)cf[idx * 3 + 0];
                    const long long c1 = (long long)(int)cf[idx * 3 + 1];
                    const long long c2 = (long long)(int)cf[idx * 3 + 2];
                    const long long xi = (long long)(n0[k] - 896);
                    long long r2 = (c2 * xi + c1) * xi + c0;
                    if (r2 < 0) r2 = 0;
                    e0[k] = (int)(r2 >> 15);
                    t0 += e0[k];
                }
                {
                    const int u  = n1[k] - 768;
                    const int uc = u < 0 ? 0 : u;
                    int idx = ((uc + 1) * 257) >> 12;
                    idx = idx > 15 ? 15 : idx;
                    const long long c0 = (long long)(int)cf[idx * 3 + 0];
                    const long long c1 = (long long)(int)cf[idx * 3 + 1];
                    const long long c2 = (long long)(int)cf[idx * 3 + 2];
                    const long long xi = (long long)(n1[k] - 896);
                    long long r2 = (c2 * xi + c1) * xi + c0;
                    if (r2 < 0) r2 = 0;
                    e1[k] = (int)(r2 >> 15);
                    t1 += e1[k];
                }
            }
        }

        // two independent DPP sum chains interleave
        DPP_SUM_I32(t0)
        DPP_SUM_I32(t1)
        int ts0 = __builtin_amdgcn_readlane(t0, 63);
        int ts1 = __builtin_amdgcn_readlane(t1, 63);
        if (ts0 < 1) ts0 = 1;
        if (ts1 < 1) ts1 = 1;

        // factor = floor(RN64(2^32/exp_sum)) == numpy; fits u32 (sum >= ~2^13)
        const unsigned int fac0 =
            (unsigned int)floor(__ddiv_rn(4294967296.0, (double)ts0));
        const unsigned int fac1 =
            (unsigned int)floor(__ddiv_rn(4294967296.0, (double)ts1));
        const unsigned int f70 = fac0 << 7;     // factor < 2^20: no overflow
        const unsigned int f71 = fac1 << 7;

        // softmax_int = (e*factor)>>25 == umulhi(e, factor<<7); out = si * 2^-7
        nfloat4 oa0, ob0, oa1, ob1;
        #pragma unroll
        for (int k = 0; k < 4; ++k) {
            oa0[k] = (float)__umulhi((unsigned int)e0[k],     f70) * 0.0078125f;
            ob0[k] = (float)__umulhi((unsigned int)e0[k + 4], f70) * 0.0078125f;
            oa1[k] = (float)__umulhi((unsigned int)e1[k],     f71) * 0.0078125f;
            ob1[k] = (float)__umulhi((unsigned int)e1[k + 4], f71) * 0.0078125f;
        }

        {
            nfloat4* op = ob + base + lane;
            __builtin_nontemporal_store(oa0, op);
            __builtin_nontemporal_store(ob0, op + 64);
            __builtin_nontemporal_store(oa1, op + 128);
            __builtin_nontemporal_store(ob1, op + 192);
        }

        if (sg == 0 && wid == 0 && lane == 0)
            out[(long long)nrows * ROWLEN] = 0.0078125f;   // second output: s_out

        if (!more) break;
        sg   = nxt;
        base = nbase;
        va0 = pa0; vb0 = pb0; va1 = pa1; vb1 = pb1;
    }
}

extern "C" void kernel_launch(void* const* d_in, const int* in_sizes, int n_in,
                              void* d_out, int out_size, void* d_ws, size_t ws_size,
                              hipStream_t stream) {
    const float* x  = (const float*)d_in[0];
    const float* sf = (const float*)d_in[1];
    const float* lo = (const float*)d_in[2];
    const float* cf = (const float*)d_in[3];
    float* out = (float*)d_out;

    const int nrows = in_sizes[0] / ROWLEN;   // 49152
    const int nsg   = nrows / 8;              // 6144 supergroups (8 rows each)
    const int grid  = nsg < 2048 ? nsg : 2048;   // 8 blocks/CU, persistent
    ppis_kernel<<<grid, 256, 0, stream>>>(x, sf, lo, cf, out, nrows);
}

// Round 3
// 187.582 us; speedup vs baseline: 1.0990x; 1.0990x over previous
//
#include <hip/hip_runtime.h>

// PPolyIntSoftmax, rows of 512. Exact float64-numpy replication.
// R12: R11's 2-rows/wave structure with the register budget it needs.
//  R11 post-mortem: __launch_bounds__(256,8) capped VGPR at 64; the 2-row
//  structure needs ~80 live regs -> compiler spilled to scratch. Evidence:
//  WRITE_SIZE 98->155 MB (+57% with identical semantics) = spill round-trips.
//  Fix: __launch_bounds__(256,4) -> 128 VGPR budget, grid = 1024 persistent
//  blocks (4/CU, 16 waves/CU). Per-wave: 2 independent row chains + 4KB
//  prefetch in flight; per-CU MLP preserved at half the wave count.
//  - 32-bit indexing in the hot loop; offsets fold to offset:1024/2048/3072.
//  - LUT built once per block; single __syncthreads; steady loop barrier-free.
//  - exact-integer semantics unchanged from R9/R10/R11 (absmax=0): fdiv_floor
//    two-fma correction, LUT Horner (i32/i64 exact), DPP i32 sum,
//    factor via __ddiv_rn, (e*factor)>>25 == umulhi(e, factor<<7).

#define ROWLEN 512

typedef float nfloat4 __attribute__((ext_vector_type(4)));

#define DPP_SUM_I32(t)                                                        \
    t += __builtin_amdgcn_update_dpp(0, t, 0x111, 0xf, 0xf, true);            \
    t += __builtin_amdgcn_update_dpp(0, t, 0x112, 0xf, 0xf, true);            \
    t += __builtin_amdgcn_update_dpp(0, t, 0x114, 0xf, 0xf, true);            \
    t += __builtin_amdgcn_update_dpp(0, t, 0x118, 0xf, 0xf, true);            \
    t += __builtin_amdgcn_update_dpp(0, t, 0x142, 0xa, 0xf, true);            \
    t += __builtin_amdgcn_update_dpp(0, t, 0x143, 0xc, 0xf, true);

#define DPP_MAX_I32_STEP(m, ctrl, rmask)                                      \
    {                                                                         \
        int _sh = __builtin_amdgcn_update_dpp(m, m, ctrl, rmask, 0xf, false); \
        m = (_sh > m) ? _sh : m;                                              \
    }

#define DPP_MAX_CHAIN(m)                                                      \
    DPP_MAX_I32_STEP(m, 0x111, 0xf)                                           \
    DPP_MAX_I32_STEP(m, 0x112, 0xf)                                           \
    DPP_MAX_I32_STEP(m, 0x114, 0xf)                                           \
    DPP_MAX_I32_STEP(m, 0x118, 0xf)                                           \
    DPP_MAX_I32_STEP(m, 0x142, 0xa)                                           \
    DPP_MAX_I32_STEP(m, 0x143, 0xc)

__global__ __launch_bounds__(256, 4) void ppis_kernel(
    const float* __restrict__ x,
    const float* __restrict__ sfp,
    const float* __restrict__ lo,   // unused: structure derived analytically
    const float* __restrict__ cf,
    float* __restrict__ out,
    int nrows)
{
    __shared__ int s_e[1024];   // exp_int LUT: entry j <-> xi = j - 896

    const int tid  = threadIdx.x;
    const int lane = tid & 63;
    const int wid  = tid >> 6;

    const int nsg     = nrows >> 3;       // supergroups of 8 rows (2 rows/wave)
    const int gstride = (int)gridDim.x;

    int sg = (int)blockIdx.x;

    // ---- issue first x loads (2 rows/wave); LUT build overlaps latency ----
    const float4* xb = reinterpret_cast<const float4*>(x);
    int base = (sg * 8 + wid * 2) * (ROWLEN / 4);   // row r0 base, float4 units
    float4 va0 = xb[base + lane];
    float4 vb0 = xb[base + 64 + lane];
    float4 va1 = xb[base + 128 + lane];
    float4 vb1 = xb[base + 192 + lane];

    const float s  = sfp[0];
    const float ry = 1.0f / s;   // approx reciprocal; exactness via fma sign tests

    // ---- build LUT ONCE per block: bit-identical integer pipeline ----
    {
        int4 ev;
        int* evp = reinterpret_cast<int*>(&ev);
        const int j0 = tid * 4;
        #pragma unroll
        for (int jj = 0; jj < 4; ++jj) {
            const int j  = j0 + jj;
            const int u  = j - 768;              // u = xi + 128
            const int uc = u < 0 ? 0 : u;
            int idx = ((uc + 1) * 257) >> 12;    // == clip(searchsorted-1,0,15)
            idx = idx > 15 ? 15 : idx;
            const int c0 = (int)cf[idx * 3 + 0];
            const int c1 = (int)cf[idx * 3 + 1];
            const int c2 = (int)cf[idx * 3 + 2];
            const int xi = j - 896;              // UNCLAMPED xi
            const int r1 = c2 * xi + c1;               // |c2*xi| < 2^27: exact i32
            long long r2 = (long long)r1 * xi + c0;    // exact i64
            if (r2 < 0) r2 = 0;
            evp[jj] = (int)(r2 >> 15);
        }
        reinterpret_cast<int4*>(s_e)[tid] = ev;  // ds_write_b128
    }
    __syncthreads();            // the ONLY barrier; LUT read-only afterwards

    nfloat4* ob = reinterpret_cast<nfloat4*>(out);

    // exact floor(x/s), f32 only (validated absmax=0 since R6)
    auto fdiv_floor = [&](float xk) -> int {
        float nf = floorf(xk * ry);                 // candidate, off by <=1
        const float d = fmaf(-s, nf, xk);           // sign(x - nf*s) exact
        nf = (d < 0.0f) ? nf - 1.0f : nf;
        const float u = fmaf(-s, nf + 1.0f, xk);    // sign(x - (nf+1)s) exact
        nf = (u >= 0.0f) ? nf + 1.0f : nf;
        return (int)nf;
    };

    while (true) {
        // ---- prefetch next supergroup's 2 rows before processing current ----
        const int nxt   = sg + gstride;
        const bool more = nxt < nsg;
        const int nbase = (nxt * 8 + wid * 2) * (ROWLEN / 4);
        float4 pa0, pb0, pa1, pb1;
        if (more) {
            pa0 = xb[nbase + lane];
            pb0 = xb[nbase + 64 + lane];
            pa1 = xb[nbase + 128 + lane];
            pb1 = xb[nbase + 192 + lane];
        }

        const float xv0[8] = {va0.x, va0.y, va0.z, va0.w, vb0.x, vb0.y, vb0.z, vb0.w};
        const float xv1[8] = {va1.x, va1.y, va1.z, va1.w, vb1.x, vb1.y, vb1.z, vb1.w};

        int n0[8], n1[8];
        #pragma unroll
        for (int k = 0; k < 8; ++k) n0[k] = fdiv_floor(xv0[k]);
        #pragma unroll
        for (int k = 0; k < 8; ++k) n1[k] = fdiv_floor(xv1[k]);

        // row maxes in INT domain — two independent DPP chains interleave
        int m0 = n0[0], m1 = n1[0];
        #pragma unroll
        for (int k = 1; k < 8; ++k) {
            m0 = (n0[k] > m0) ? n0[k] : m0;
            m1 = (n1[k] > m1) ? n1[k] : m1;
        }
        DPP_MAX_CHAIN(m0)
        DPP_MAX_CHAIN(m1)
        const int mx0 = __builtin_amdgcn_readlane(m0, 63);
        const int mx1 = __builtin_amdgcn_readlane(m1, 63);

        const int joff0 = 1023 - mx0;           // j = n + joff, j <= 1023
        const int joff1 = 1023 - mx1;

        int jmin;
        {
            #pragma unroll
            for (int k = 0; k < 8; ++k) { n0[k] += joff0; n1[k] += joff1; }
            jmin = n0[0];
            #pragma unroll
            for (int k = 1; k < 8; ++k) jmin = (n0[k] < jmin) ? n0[k] : jmin;
            #pragma unroll
            for (int k = 0; k < 8; ++k) jmin = (n1[k] < jmin) ? n1[k] : jmin;
        }

        int e0[8], e1[8];
        int t0 = 0, t1 = 0;
        if (!__any(jmin < 0)) {
            // fast path: both rows fully inside the LUT domain
            #pragma unroll
            for (int k = 0; k < 8; ++k) {
                e0[k] = s_e[n0[k]];
                e1[k] = s_e[n1[k]];
                t0 += e0[k];
                t1 += e1[k];
            }
        } else {
            // rare: row span > 1023 ints -> exact i64 Horner at actual xi
            // (identical formulas to the LUT build -> bit-identical values)
            #pragma unroll 1
            for (int k = 0; k < 8; ++k) {
                {
                    const int u  = n0[k] - 768;
                    const int uc = u < 0 ? 0 : u;
                    int idx = ((uc + 1) * 257) >> 12;
                    idx = idx > 15 ? 15 : idx;
                    const long long c0 = (long long)(int)cf[idx * 3 + 0];
                    const long long c1 = (long long)(int)cf[idx * 3 + 1];
                    const long long c2 = (long long)(int)cf[idx * 3 + 2];
                    const long long xi = (long long)(n0[k] - 896);
                    long long r2 = (c2 * xi + c1) * xi + c0;
                    if (r2 < 0) r2 = 0;
                    e0[k] = (int)(r2 >> 15);
                    t0 += e0[k];
                }
                {
                    const int u  = n1[k] - 768;
                    const int uc = u < 0 ? 0 : u;
                    int idx = ((uc + 1) * 257) >> 12;
                    idx = idx > 15 ? 15 : idx;
                    const long long c0 = (long long)(int)cf[idx * 3 + 0];
                    const long long c1 = (long long)(int)cf[idx * 3 + 1];
                    const long long c2 = (long long)(int)cf[idx * 3 + 2];
                    const long long xi = (long long)(n1[k] - 896);
                    long long r2 = (c2 * xi + c1) * xi + c0;
                    if (r2 < 0) r2 = 0;
                    e1[k] = (int)(r2 >> 15);
                    t1 += e1[k];
                }
            }
        }

        // two independent DPP sum chains interleave
        DPP_SUM_I32(t0)
        DPP_SUM_I32(t1)
        int ts0 = __builtin_amdgcn_readlane(t0, 63);
        int ts1 = __builtin_amdgcn_readlane(t1, 63);
        if (ts0 < 1) ts0 = 1;
        if (ts1 < 1) ts1 = 1;

        // factor = floor(RN64(2^32/exp_sum)) == numpy; fits u32 (sum >= ~2^13)
        const unsigned int fac0 =
            (unsigned int)floor(__ddiv_rn(4294967296.0, (double)ts0));
        const unsigned int fac1 =
            (unsigned int)floor(__ddiv_rn(4294967296.0, (double)ts1));
        const unsigned int f70 = fac0 << 7;     // factor < 2^20: no overflow
        const unsigned int f71 = fac1 << 7;

        // softmax_int = (e*factor)>>25 == umulhi(e, factor<<7); out = si * 2^-7
        nfloat4 oa0, ob0, oa1, ob1;
        #pragma unroll
        for (int k = 0; k < 4; ++k) {
            oa0[k] = (float)__umulhi((unsigned int)e0[k],     f70) * 0.0078125f;
            ob0[k] = (float)__umulhi((unsigned int)e0[k + 4], f70) * 0.0078125f;
            oa1[k] = (float)__umulhi((unsigned int)e1[k],     f71) * 0.0078125f;
            ob1[k] = (float)__umulhi((unsigned int)e1[k + 4], f71) * 0.0078125f;
        }

        {
            nfloat4* op = ob + base + lane;
            __builtin_nontemporal_store(oa0, op);
            __builtin_nontemporal_store(ob0, op + 64);
            __builtin_nontemporal_store(oa1, op + 128);
            __builtin_nontemporal_store(ob1, op + 192);
        }

        if (sg == 0 && wid == 0 && lane == 0)
            out[(long long)nrows * ROWLEN] = 0.0078125f;   // second output: s_out

        if (!more) break;
        sg   = nxt;
        base = nbase;
        va0 = pa0; vb0 = pb0; va1 = pa1; vb1 = pb1;
    }
}

extern "C" void kernel_launch(void* const* d_in, const int* in_sizes, int n_in,
                              void* d_out, int out_size, void* d_ws, size_t ws_size,
                              hipStream_t stream) {
    const float* x  = (const float*)d_in[0];
    const float* sf = (const float*)d_in[1];
    const float* lo = (const float*)d_in[2];
    const float* cf = (const float*)d_in[3];
    float* out = (float*)d_out;

    const int nrows = in_sizes[0] / ROWLEN;   // 49152
    const int nsg   = nrows / 8;              // 6144 supergroups (8 rows each)
    const int grid  = nsg < 1024 ? nsg : 1024;   // 4 blocks/CU, persistent
    ppis_kernel<<<grid, 256, 0, stream>>>(x, sf, lo, cf, out, nrows);
}